// Round 1
// baseline (2150.534 us; speedup 1.0000x reference)
//
#include <hip/hip_runtime.h>
#include <hip/hip_bf16.h>

#define D 64
#define N_USERS 100000
#define N_ITEMS 50000
#define N_ENT   200000

// ---------------------------------------------------------------------------
// KG message scatter: for each edge e, msg = ent[tail[e]] * relw[etype[e]];
// atomicAdd into agg[head[e]]. One thread per (edge, dim); each wave = 1 edge.
// ---------------------------------------------------------------------------
__global__ __launch_bounds__(256) void kg_scatter(
    const float* __restrict__ ent, const float* __restrict__ relw,
    const int* __restrict__ head, const int* __restrict__ tail,
    const int* __restrict__ etype, float* __restrict__ agg, int n_edges) {
  long long gid = (long long)blockIdx.x * blockDim.x + threadIdx.x;
  long long total = (long long)n_edges * D;
  if (gid >= total) return;
  int e   = (int)(gid >> 6);
  int dim = (int)(gid & 63);
  int t = tail[e];
  int h = head[e];
  int r = etype[e];
  float v = ent[(long long)t * D + dim] * relw[r * D + dim];
  atomicAdd(&agg[(long long)h * D + dim], v);
}

// ---------------------------------------------------------------------------
// Interaction scatter: i_u_agg[mat_col[e]] += usr[mat_row[e]] * relw[0]
// ---------------------------------------------------------------------------
__global__ __launch_bounds__(256) void inter_scatter(
    const float* __restrict__ usr, const float* __restrict__ relw0,
    const int* __restrict__ mrow, const int* __restrict__ mcol,
    float* __restrict__ iu, int n_inter) {
  long long gid = (long long)blockIdx.x * blockDim.x + threadIdx.x;
  long long total = (long long)n_inter * D;
  if (gid >= total) return;
  int e   = (int)(gid >> 6);
  int dim = (int)(gid & 63);
  int r = mrow[e];
  int c = mcol[e];
  float v = usr[(long long)r * D + dim] * relw0[dim];
  atomicAdd(&iu[(long long)c * D + dim], v);
}

// ---------------------------------------------------------------------------
// Gate + fusion for item rows:
//   s_j   = sum_k ea[k]*G1[j][k] + iu[k]*G2[j][k]
//   gi    = leaky_relu(s, 0.2)
//   fus_j = gi_j*ea_j + (1-gi_j)*iu_j   (written over ent_agg row in place)
// One wave per row; G1/G2 staged in LDS padded [64][65] -> conflict-free.
// ---------------------------------------------------------------------------
__global__ __launch_bounds__(256) void fuse_items(
    float* __restrict__ ent_agg, const float* __restrict__ iu,
    const float* __restrict__ g1, const float* __restrict__ g2, int n_items) {
  __shared__ float G1[D][D + 1];
  __shared__ float G2[D][D + 1];
  for (int i = threadIdx.x; i < D * D; i += blockDim.x) {
    G1[i >> 6][i & 63] = g1[i];
    G2[i >> 6][i & 63] = g2[i];
  }
  __syncthreads();
  int wave = threadIdx.x >> 6;
  int lane = threadIdx.x & 63;
  int row = blockIdx.x * 4 + wave;
  if (row >= n_items) return;
  float ea = ent_agg[(long long)row * D + lane];
  float u  = iu[(long long)row * D + lane];
  float s = 0.f;
#pragma unroll 8
  for (int k = 0; k < D; ++k) {
    float eak = __shfl(ea, k);
    float uk  = __shfl(u, k);
    s += eak * G1[lane][k] + uk * G2[lane][k];
  }
  float gi = s > 0.f ? s : 0.2f * s;
  float fus = gi * ea + (1.f - gi) * u;
  ent_agg[(long long)row * D + lane] = fus;
}

// ---------------------------------------------------------------------------
// user_agg[mat_row[e]] += item_fusion[mat_col[e]]
// ---------------------------------------------------------------------------
__global__ __launch_bounds__(256) void user_scatter(
    const float* __restrict__ fus, const int* __restrict__ mrow,
    const int* __restrict__ mcol, float* __restrict__ uagg, int n_inter) {
  long long gid = (long long)blockIdx.x * blockDim.x + threadIdx.x;
  long long total = (long long)n_inter * D;
  if (gid >= total) return;
  int e   = (int)(gid >> 6);
  int dim = (int)(gid & 63);
  int c = mcol[e];
  int r = mrow[e];
  float v = fus[(long long)c * D + dim];
  atomicAdd(&uagg[(long long)r * D + dim], v);
}

// ---------------------------------------------------------------------------
// Row L2-normalize in place + accumulate into residual. One wave per row.
// ---------------------------------------------------------------------------
__global__ __launch_bounds__(256) void normalize_add(
    float* __restrict__ x, float* __restrict__ res, int n_rows) {
  int row = blockIdx.x * 4 + (threadIdx.x >> 6);
  int lane = threadIdx.x & 63;
  if (row >= n_rows) return;
  long long idx = (long long)row * D + lane;
  float v = x[idx];
  float ss = v * v;
#pragma unroll
  for (int m = 1; m < 64; m <<= 1) ss += __shfl_xor(ss, m);
  float n = sqrtf(ss);
  float scale = 1.f / fmaxf(n, 1e-12f);
  float nv = v * scale;
  x[idx] = nv;
  res[idx] += nv;
}

extern "C" void kernel_launch(void* const* d_in, const int* in_sizes, int n_in,
                              void* d_out, int out_size, void* d_ws, size_t ws_size,
                              hipStream_t stream) {
  const float* user_emb = (const float*)d_in[0];
  const float* ent_emb  = (const float*)d_in[1];
  const float* relw     = (const float*)d_in[2];
  const float* g1       = (const float*)d_in[3];
  const float* g2       = (const float*)d_in[4];
  const int*   head     = (const int*)d_in[5];
  const int*   tail     = (const int*)d_in[6];
  const int*   etype    = (const int*)d_in[7];
  const int*   mrow     = (const int*)d_in[8];
  const int*   mcol     = (const int*)d_in[9];

  const int n_edges = in_sizes[5];
  const int n_inter = in_sizes[8];
  const int n_hops  = in_sizes[3] / (D * D);

  float* ws   = (float*)d_ws;
  float* entA = ws;
  float* entB = entA + (size_t)N_ENT * D;
  float* usrA = entB + (size_t)N_ENT * D;
  float* usrB = usrA + (size_t)N_USERS * D;
  float* iu   = usrB + (size_t)N_USERS * D;

  float* out_ent = (float*)d_out;
  float* out_usr = out_ent + (size_t)N_ENT * D;

  // residuals start as the raw input embeddings
  hipMemcpyAsync(out_ent, ent_emb, (size_t)N_ENT * D * sizeof(float),
                 hipMemcpyDeviceToDevice, stream);
  hipMemcpyAsync(out_usr, user_emb, (size_t)N_USERS * D * sizeof(float),
                 hipMemcpyDeviceToDevice, stream);

  const float* cur_ent = ent_emb;
  const float* cur_usr = user_emb;

  for (int i = 0; i < n_hops; ++i) {
    float* ea = (i & 1) ? entB : entA;
    float* ua = (i & 1) ? usrB : usrA;

    hipMemsetAsync(ea, 0, (size_t)N_ENT * D * sizeof(float), stream);
    hipMemsetAsync(ua, 0, (size_t)N_USERS * D * sizeof(float), stream);
    hipMemsetAsync(iu, 0, (size_t)N_ITEMS * D * sizeof(float), stream);

    long long tk = (long long)n_edges * D;
    kg_scatter<<<(int)((tk + 255) / 256), 256, 0, stream>>>(
        cur_ent, relw, head, tail, etype, ea, n_edges);

    long long ti = (long long)n_inter * D;
    inter_scatter<<<(int)((ti + 255) / 256), 256, 0, stream>>>(
        cur_usr, relw, mrow, mcol, iu, n_inter);

    fuse_items<<<(N_ITEMS + 3) / 4, 256, 0, stream>>>(
        ea, iu, g1 + (size_t)i * D * D, g2 + (size_t)i * D * D, N_ITEMS);

    user_scatter<<<(int)((ti + 255) / 256), 256, 0, stream>>>(
        ea, mrow, mcol, ua, n_inter);

    normalize_add<<<(N_ENT + 3) / 4, 256, 0, stream>>>(ea, out_ent, N_ENT);
    normalize_add<<<(N_USERS + 3) / 4, 256, 0, stream>>>(ua, out_usr, N_USERS);

    cur_ent = ea;
    cur_usr = ua;
  }
}

// Round 2
// 1863.303 us; speedup vs baseline: 1.1542x; 1.1542x over previous
//
#include <hip/hip_runtime.h>
#include <hip/hip_bf16.h>

#define D 64
#define N_USERS 100000
#define N_ITEMS 50000
#define N_ENT   200000
#define EPS 1e-12f

// ============================ CSR build =====================================
__global__ __launch_bounds__(256) void hist_kernel(
    const int* __restrict__ idx, int* __restrict__ cnt, int n) {
  int i = blockIdx.x * 256 + threadIdx.x;
  if (i < n) atomicAdd(&cnt[idx[i]], 1);
}

// 256-elem inclusive scan per block -> exclusive out + block total
__global__ __launch_bounds__(256) void scan_block(
    const int* __restrict__ in, int* __restrict__ out,
    int* __restrict__ bsum, int n) {
  __shared__ int sm[256];
  int tid = threadIdx.x;
  int i = blockIdx.x * 256 + tid;
  int v = (i < n) ? in[i] : 0;
  sm[tid] = v;
  __syncthreads();
  for (int ofs = 1; ofs < 256; ofs <<= 1) {
    int t = (tid >= ofs) ? sm[tid - ofs] : 0;
    __syncthreads();
    sm[tid] += t;
    __syncthreads();
  }
  if (i < n) out[i] = sm[tid] - v;  // exclusive
  if (tid == 255) bsum[blockIdx.x] = sm[255];
}

// single-block scan of block sums (nb <= 1024 always here: max 782)
__global__ __launch_bounds__(1024) void scan_top(int* __restrict__ bsum, int nb) {
  __shared__ int sm[1024];
  int tid = threadIdx.x;
  int v = (tid < nb) ? bsum[tid] : 0;
  sm[tid] = v;
  __syncthreads();
  for (int ofs = 1; ofs < 1024; ofs <<= 1) {
    int t = (tid >= ofs) ? sm[tid - ofs] : 0;
    __syncthreads();
    sm[tid] += t;
    __syncthreads();
  }
  if (tid < nb) bsum[tid] = sm[tid] - v;  // exclusive
}

__global__ __launch_bounds__(256) void scan_add(
    int* __restrict__ out, const int* __restrict__ bsum, int n, int total) {
  int i = blockIdx.x * 256 + threadIdx.x;
  if (i < n) out[i] += bsum[blockIdx.x];
  if (i == 0) out[n] = total;  // tail sentinel so off[h+1] always valid
}

__global__ __launch_bounds__(256) void fill_csr(
    const int* __restrict__ idx, int* __restrict__ cur,
    int* __restrict__ elist, int n) {
  int i = blockIdx.x * 256 + threadIdx.x;
  if (i < n) {
    int p = atomicAdd(&cur[idx[i]], 1);
    elist[p] = i;
  }
}

// ============================ per-hop kernels ===============================
// One wave per head entity: register-accumulate its in-edges, single store.
// For h >= N_ITEMS the row is final -> normalize + residual here.
__global__ __launch_bounds__(256) void kg_gather(
    const float* __restrict__ ent, const float* __restrict__ relw,
    const int* __restrict__ tail, const int* __restrict__ etype,
    const int* __restrict__ off, const int* __restrict__ elist,
    float* __restrict__ agg, float* __restrict__ res) {
  int h = blockIdx.x * 4 + (threadIdx.x >> 6);
  if (h >= N_ENT) return;
  int lane = threadIdx.x & 63;
  int b = off[h], e = off[h + 1];
  float acc = 0.f;
  for (int j = b; j < e; ++j) {
    int ed = __builtin_amdgcn_readfirstlane(elist[j]);
    int t = tail[ed];
    int r = etype[ed];
    acc += ent[t * D + lane] * relw[r * D + lane];
  }
  int o = h * D + lane;
  if (h < N_ITEMS) {
    agg[o] = acc;  // raw: fuse_items consumes this
  } else {
    float ss = acc * acc;
#pragma unroll
    for (int m = 1; m < 64; m <<= 1) ss += __shfl_xor(ss, m);
    float nv = acc / fmaxf(sqrtf(ss), EPS);
    agg[o] = nv;
    res[o] += nv;
  }
}

// i_u_agg[c] = (sum of usr rows) * relw[0]  (relw0 factored out of the loop)
__global__ __launch_bounds__(256) void inter_gather(
    const float* __restrict__ usr, const float* __restrict__ relw,
    const int* __restrict__ mrow, const int* __restrict__ off,
    const int* __restrict__ elist, float* __restrict__ iu) {
  int c = blockIdx.x * 4 + (threadIdx.x >> 6);
  if (c >= N_ITEMS) return;
  int lane = threadIdx.x & 63;
  int b = off[c], e = off[c + 1];
  float acc = 0.f;
  for (int j = b; j < e; ++j) {
    int ed = __builtin_amdgcn_readfirstlane(elist[j]);
    int r = mrow[ed];
    acc += usr[r * D + lane];
  }
  iu[c * D + lane] = acc * relw[lane];
}

// gate GEMM + fusion; writes RAW fusion into iu (for user_gather) and
// NORMALIZED fusion into ea (next-hop entity emb) + residual.
__global__ __launch_bounds__(256) void fuse_items(
    float* __restrict__ ea, float* __restrict__ iu,
    const float* __restrict__ g1, const float* __restrict__ g2,
    float* __restrict__ res) {
  __shared__ float G1[D][D + 1];
  __shared__ float G2[D][D + 1];
  for (int i = threadIdx.x; i < D * D; i += 256) {
    G1[i >> 6][i & 63] = g1[i];
    G2[i >> 6][i & 63] = g2[i];
  }
  __syncthreads();
  int row = blockIdx.x * 4 + (threadIdx.x >> 6);
  if (row >= N_ITEMS) return;
  int lane = threadIdx.x & 63;
  int o = row * D + lane;
  float eav = ea[o];
  float uv = iu[o];
  float s = 0.f;
#pragma unroll 8
  for (int k = 0; k < D; ++k) {
    s += __shfl(eav, k) * G1[lane][k] + __shfl(uv, k) * G2[lane][k];
  }
  float gi = s > 0.f ? s : 0.2f * s;
  float fus = gi * eav + (1.f - gi) * uv;
  iu[o] = fus;  // raw fusion (user_gather input)
  float ss = fus * fus;
#pragma unroll
  for (int m = 1; m < 64; m <<= 1) ss += __shfl_xor(ss, m);
  float nv = fus / fmaxf(sqrtf(ss), EPS);
  ea[o] = nv;  // normalized (next-hop entity embedding)
  res[o] += nv;
}

// user_agg[u] = sum of raw fusion rows; normalize + residual fused.
__global__ __launch_bounds__(256) void user_gather(
    const float* __restrict__ fus, const int* __restrict__ mcol,
    const int* __restrict__ off, const int* __restrict__ elist,
    float* __restrict__ ua, float* __restrict__ res) {
  int u = blockIdx.x * 4 + (threadIdx.x >> 6);
  if (u >= N_USERS) return;
  int lane = threadIdx.x & 63;
  int b = off[u], e = off[u + 1];
  float acc = 0.f;
  for (int j = b; j < e; ++j) {
    int ed = __builtin_amdgcn_readfirstlane(elist[j]);
    int c = mcol[ed];
    acc += fus[c * D + lane];
  }
  float ss = acc * acc;
#pragma unroll
  for (int m = 1; m < 64; m <<= 1) ss += __shfl_xor(ss, m);
  float nv = acc / fmaxf(sqrtf(ss), EPS);
  int o = u * D + lane;
  ua[o] = nv;
  res[o] += nv;
}

// ============================ launch ========================================
extern "C" void kernel_launch(void* const* d_in, const int* in_sizes, int n_in,
                              void* d_out, int out_size, void* d_ws, size_t ws_size,
                              hipStream_t stream) {
  const float* user_emb = (const float*)d_in[0];
  const float* ent_emb  = (const float*)d_in[1];
  const float* relw     = (const float*)d_in[2];
  const float* g1       = (const float*)d_in[3];
  const float* g2       = (const float*)d_in[4];
  const int*   head     = (const int*)d_in[5];
  const int*   tail     = (const int*)d_in[6];
  const int*   etype    = (const int*)d_in[7];
  const int*   mrow     = (const int*)d_in[8];
  const int*   mcol     = (const int*)d_in[9];

  const int n_edges = in_sizes[5];
  const int n_inter = in_sizes[8];
  const int n_hops  = in_sizes[3] / (D * D);

  // ---- workspace carve (floats then ints) ----
  float* entA = (float*)d_ws;
  float* entB = entA + (size_t)N_ENT * D;
  float* usr  = entB + (size_t)N_ENT * D;   // single buffer: read/write in
                                            // different kernels -> no race
  float* iu   = usr + (size_t)N_USERS * D;
  int* ip = (int*)(iu + (size_t)N_ITEMS * D);
  int* c_head = ip;            ip += N_ENT;
  int* o_head = ip;            ip += N_ENT + 1;
  int* e_head = ip;            ip += n_edges;
  int* c_col  = ip;            ip += N_ITEMS;
  int* o_col  = ip;            ip += N_ITEMS + 1;
  int* e_col  = ip;            ip += n_inter;
  int* c_row  = ip;            ip += N_USERS;
  int* o_row  = ip;            ip += N_USERS + 1;
  int* e_row  = ip;            ip += n_inter;
  int* bsum   = ip;            ip += 1024;

  float* out_ent = (float*)d_out;
  float* out_usr = out_ent + (size_t)N_ENT * D;

  // residuals start as the raw input embeddings
  hipMemcpyAsync(out_ent, ent_emb, (size_t)N_ENT * D * sizeof(float),
                 hipMemcpyDeviceToDevice, stream);
  hipMemcpyAsync(out_usr, user_emb, (size_t)N_USERS * D * sizeof(float),
                 hipMemcpyDeviceToDevice, stream);

  // ---- build the three CSRs once (index arrays are hop-invariant) ----
  auto build = [&](const int* idx, int n, int nseg, int* cnt, int* off,
                   int* elist) {
    hipMemsetAsync(cnt, 0, (size_t)nseg * sizeof(int), stream);
    int nbh = (n + 255) / 256;
    hist_kernel<<<nbh, 256, 0, stream>>>(idx, cnt, n);
    int nbs = (nseg + 255) / 256;
    scan_block<<<nbs, 256, 0, stream>>>(cnt, off, bsum, nseg);
    scan_top<<<1, 1024, 0, stream>>>(bsum, nbs);
    scan_add<<<nbs, 256, 0, stream>>>(off, bsum, nseg, n);
    hipMemcpyAsync(cnt, off, (size_t)nseg * sizeof(int),
                   hipMemcpyDeviceToDevice, stream);  // cursor = offsets
    fill_csr<<<nbh, 256, 0, stream>>>(idx, cnt, elist, n);
  };
  build(head, n_edges, N_ENT, c_head, o_head, e_head);
  build(mcol, n_inter, N_ITEMS, c_col, o_col, e_col);
  build(mrow, n_inter, N_USERS, c_row, o_row, e_row);

  const float* cur_ent = ent_emb;
  const float* cur_usr = user_emb;

  for (int i = 0; i < n_hops; ++i) {
    float* ea = (i & 1) ? entB : entA;

    kg_gather<<<(N_ENT + 3) / 4, 256, 0, stream>>>(
        cur_ent, relw, tail, etype, o_head, e_head, ea, out_ent);

    inter_gather<<<(N_ITEMS + 3) / 4, 256, 0, stream>>>(
        cur_usr, relw, mrow, o_col, e_col, iu);

    fuse_items<<<(N_ITEMS + 3) / 4, 256, 0, stream>>>(
        ea, iu, g1 + (size_t)i * D * D, g2 + (size_t)i * D * D, out_ent);

    user_gather<<<(N_USERS + 3) / 4, 256, 0, stream>>>(
        iu, mcol, o_row, e_row, usr, out_usr);

    cur_ent = ea;
    cur_usr = usr;
  }
}

// Round 3
// 1053.274 us; speedup vs baseline: 2.0418x; 1.7691x over previous
//
#include <hip/hip_runtime.h>
#include <hip/hip_bf16.h>

#define D 64
#define N_USERS 100000
#define N_ITEMS 50000
#define N_ENT   200000
#define EPS 1e-12f

// ============================ CSR build =====================================
__global__ __launch_bounds__(256) void hist_kernel(
    const int* __restrict__ idx, int* __restrict__ cnt, int n) {
  int i = blockIdx.x * 256 + threadIdx.x;
  if (i < n) atomicAdd(&cnt[idx[i]], 1);
}

// 256-elem inclusive scan per block -> exclusive out + block total
__global__ __launch_bounds__(256) void scan_block(
    const int* __restrict__ in, int* __restrict__ out,
    int* __restrict__ bsum, int n) {
  __shared__ int sm[256];
  int tid = threadIdx.x;
  int i = blockIdx.x * 256 + tid;
  int v = (i < n) ? in[i] : 0;
  sm[tid] = v;
  __syncthreads();
  for (int ofs = 1; ofs < 256; ofs <<= 1) {
    int t = (tid >= ofs) ? sm[tid - ofs] : 0;
    __syncthreads();
    sm[tid] += t;
    __syncthreads();
  }
  if (i < n) out[i] = sm[tid] - v;  // exclusive
  if (tid == 255) bsum[blockIdx.x] = sm[255];
}

// single-block scan of block sums (nb <= 1024 always here: max 782)
__global__ __launch_bounds__(1024) void scan_top(int* __restrict__ bsum, int nb) {
  __shared__ int sm[1024];
  int tid = threadIdx.x;
  int v = (tid < nb) ? bsum[tid] : 0;
  sm[tid] = v;
  __syncthreads();
  for (int ofs = 1; ofs < 1024; ofs <<= 1) {
    int t = (tid >= ofs) ? sm[tid - ofs] : 0;
    __syncthreads();
    sm[tid] += t;
    __syncthreads();
  }
  if (tid < nb) bsum[tid] = sm[tid] - v;  // exclusive
}

__global__ __launch_bounds__(256) void scan_add(
    int* __restrict__ out, const int* __restrict__ bsum, int n, int total) {
  int i = blockIdx.x * 256 + threadIdx.x;
  if (i < n) out[i] += bsum[blockIdx.x];
  if (i == 0) out[n] = total;  // tail sentinel so off[h+1] always valid
}

// head CSR: store packed (tail | etype<<24) instead of the edge id
__global__ __launch_bounds__(256) void fill_csr_packed(
    const int* __restrict__ idx, const int* __restrict__ tail,
    const int* __restrict__ etype, int* __restrict__ cur,
    int* __restrict__ vals, int n) {
  int i = blockIdx.x * 256 + threadIdx.x;
  if (i < n) {
    int p = atomicAdd(&cur[idx[i]], 1);
    vals[p] = tail[i] | (etype[i] << 24);
  }
}

// generic CSR: store val[i] (the *other* endpoint) instead of the edge id
__global__ __launch_bounds__(256) void fill_csr_val(
    const int* __restrict__ idx, const int* __restrict__ val,
    int* __restrict__ cur, int* __restrict__ vals, int n) {
  int i = blockIdx.x * 256 + threadIdx.x;
  if (i < n) {
    int p = atomicAdd(&cur[idx[i]], 1);
    vals[p] = val[i];
  }
}

// ==================== pipelined segment-sum helpers =========================
// Segment indices pk[b..e) are loaded coalesced across lanes once, then
// broadcast via shfl; the 4 row-gathers per unrolled step are independent
// so the wave keeps >=4 loads in flight (vs 1 for the naive chain).
__device__ __forceinline__ float segsum_packed(
    const int* __restrict__ pk, int b, int e, int lane,
    const float* __restrict__ ent, const float* __restrict__ relw) {
  float acc = 0.f;
  for (int j0 = b; j0 < e; j0 += 64) {
    int cnt = min(64, e - j0);
    int p = (j0 + lane < e) ? pk[j0 + lane] : 0;
    int jj = 0;
    for (; jj + 4 <= cnt; jj += 4) {
      int p0 = __shfl(p, jj),     p1 = __shfl(p, jj + 1);
      int p2 = __shfl(p, jj + 2), p3 = __shfl(p, jj + 3);
      float a0 = ent[(p0 & 0xFFFFFF) * D + lane] * relw[((unsigned)p0 >> 24) * D + lane];
      float a1 = ent[(p1 & 0xFFFFFF) * D + lane] * relw[((unsigned)p1 >> 24) * D + lane];
      float a2 = ent[(p2 & 0xFFFFFF) * D + lane] * relw[((unsigned)p2 >> 24) * D + lane];
      float a3 = ent[(p3 & 0xFFFFFF) * D + lane] * relw[((unsigned)p3 >> 24) * D + lane];
      acc += (a0 + a1) + (a2 + a3);
    }
    for (; jj < cnt; ++jj) {
      int pj = __shfl(p, jj);
      acc += ent[(pj & 0xFFFFFF) * D + lane] * relw[((unsigned)pj >> 24) * D + lane];
    }
  }
  return acc;
}

__device__ __forceinline__ float segsum_idx(
    const int* __restrict__ il, int b, int e, int lane,
    const float* __restrict__ tab) {
  float acc = 0.f;
  for (int j0 = b; j0 < e; j0 += 64) {
    int cnt = min(64, e - j0);
    int p = (j0 + lane < e) ? il[j0 + lane] : 0;
    int jj = 0;
    for (; jj + 4 <= cnt; jj += 4) {
      int p0 = __shfl(p, jj),     p1 = __shfl(p, jj + 1);
      int p2 = __shfl(p, jj + 2), p3 = __shfl(p, jj + 3);
      float a0 = tab[p0 * D + lane];
      float a1 = tab[p1 * D + lane];
      float a2 = tab[p2 * D + lane];
      float a3 = tab[p3 * D + lane];
      acc += (a0 + a1) + (a2 + a3);
    }
    for (; jj < cnt; ++jj) acc += tab[__shfl(p, jj) * D + lane];
  }
  return acc;
}

__device__ __forceinline__ float wave_rsqnorm(float v) {
  float ss = v * v;
#pragma unroll
  for (int m = 1; m < 64; m <<= 1) ss += __shfl_xor(ss, m);
  return 1.f / fmaxf(sqrtf(ss), EPS);
}

// ============================ per-hop kernels ===============================
__global__ __launch_bounds__(256) void kg_gather(
    const float* __restrict__ ent, const float* __restrict__ relw,
    const int* __restrict__ off, const int* __restrict__ pk,
    float* __restrict__ agg, float* __restrict__ res) {
  int wv = __builtin_amdgcn_readfirstlane(threadIdx.x >> 6);
  int h = blockIdx.x * 4 + wv;
  if (h >= N_ENT) return;
  int lane = threadIdx.x & 63;
  int b = off[h], e = off[h + 1];
  float acc = segsum_packed(pk, b, e, lane, ent, relw);
  int o = h * D + lane;
  if (h < N_ITEMS) {
    agg[o] = acc;  // raw: fuse_items consumes this
  } else {
    float nv = acc * wave_rsqnorm(acc);
    agg[o] = nv;
    res[o] += nv;
  }
}

// i_u_agg[c] = (sum of usr rows) * relw[0]  (relw0 factored out of the loop)
__global__ __launch_bounds__(256) void inter_gather(
    const float* __restrict__ usr, const float* __restrict__ relw,
    const int* __restrict__ off, const int* __restrict__ vr,
    float* __restrict__ iu) {
  int wv = __builtin_amdgcn_readfirstlane(threadIdx.x >> 6);
  int c = blockIdx.x * 4 + wv;
  if (c >= N_ITEMS) return;
  int lane = threadIdx.x & 63;
  int b = off[c], e = off[c + 1];
  float acc = segsum_idx(vr, b, e, lane, usr);
  iu[c * D + lane] = acc * relw[lane];
}

// gate GEMM + fusion; writes RAW fusion into iu (for user_gather) and
// NORMALIZED fusion into ea (next-hop entity emb) + residual.
__global__ __launch_bounds__(256) void fuse_items(
    float* __restrict__ ea, float* __restrict__ iu,
    const float* __restrict__ g1, const float* __restrict__ g2,
    float* __restrict__ res) {
  __shared__ float G1[D][D + 1];
  __shared__ float G2[D][D + 1];
  for (int i = threadIdx.x; i < D * D; i += 256) {
    G1[i >> 6][i & 63] = g1[i];
    G2[i >> 6][i & 63] = g2[i];
  }
  __syncthreads();
  int row = blockIdx.x * 4 + (threadIdx.x >> 6);
  if (row >= N_ITEMS) return;
  int lane = threadIdx.x & 63;
  int o = row * D + lane;
  float eav = ea[o];
  float uv = iu[o];
  float s = 0.f;
#pragma unroll 8
  for (int k = 0; k < D; ++k) {
    s += __shfl(eav, k) * G1[lane][k] + __shfl(uv, k) * G2[lane][k];
  }
  float gi = s > 0.f ? s : 0.2f * s;
  float fus = gi * eav + (1.f - gi) * uv;
  iu[o] = fus;  // raw fusion (user_gather input)
  float nv = fus * wave_rsqnorm(fus);
  ea[o] = nv;  // normalized (next-hop entity embedding)
  res[o] += nv;
}

// user_agg[u] = sum of raw fusion rows; normalize + residual fused.
__global__ __launch_bounds__(256) void user_gather(
    const float* __restrict__ fus, const int* __restrict__ off,
    const int* __restrict__ vc, float* __restrict__ ua,
    float* __restrict__ res) {
  int wv = __builtin_amdgcn_readfirstlane(threadIdx.x >> 6);
  int u = blockIdx.x * 4 + wv;
  if (u >= N_USERS) return;
  int lane = threadIdx.x & 63;
  int b = off[u], e = off[u + 1];
  float acc = segsum_idx(vc, b, e, lane, fus);
  float nv = acc * wave_rsqnorm(acc);
  int o = u * D + lane;
  ua[o] = nv;
  res[o] += nv;
}

// ============================ launch ========================================
extern "C" void kernel_launch(void* const* d_in, const int* in_sizes, int n_in,
                              void* d_out, int out_size, void* d_ws, size_t ws_size,
                              hipStream_t stream) {
  const float* user_emb = (const float*)d_in[0];
  const float* ent_emb  = (const float*)d_in[1];
  const float* relw     = (const float*)d_in[2];
  const float* g1       = (const float*)d_in[3];
  const float* g2       = (const float*)d_in[4];
  const int*   head     = (const int*)d_in[5];
  const int*   tail     = (const int*)d_in[6];
  const int*   etype    = (const int*)d_in[7];
  const int*   mrow     = (const int*)d_in[8];
  const int*   mcol     = (const int*)d_in[9];

  const int n_edges = in_sizes[5];
  const int n_inter = in_sizes[8];
  const int n_hops  = in_sizes[3] / (D * D);

  // ---- workspace carve (floats then ints) ----
  float* entA = (float*)d_ws;
  float* entB = entA + (size_t)N_ENT * D;
  float* usr  = entB + (size_t)N_ENT * D;
  float* iu   = usr + (size_t)N_USERS * D;
  int* ip = (int*)(iu + (size_t)N_ITEMS * D);
  int* c_head = ip;            ip += N_ENT;
  int* o_head = ip;            ip += N_ENT + 1;
  int* pk_head = ip;           ip += n_edges;   // packed tail|etype<<24
  int* c_col  = ip;            ip += N_ITEMS;
  int* o_col  = ip;            ip += N_ITEMS + 1;
  int* vr_col = ip;            ip += n_inter;   // mrow permuted by col
  int* c_row  = ip;            ip += N_USERS;
  int* o_row  = ip;            ip += N_USERS + 1;
  int* vc_row = ip;            ip += n_inter;   // mcol permuted by row
  int* bsum   = ip;            ip += 1024;

  float* out_ent = (float*)d_out;
  float* out_usr = out_ent + (size_t)N_ENT * D;

  // residuals start as the raw input embeddings
  hipMemcpyAsync(out_ent, ent_emb, (size_t)N_ENT * D * sizeof(float),
                 hipMemcpyDeviceToDevice, stream);
  hipMemcpyAsync(out_usr, user_emb, (size_t)N_USERS * D * sizeof(float),
                 hipMemcpyDeviceToDevice, stream);

  // ---- build the three CSRs once (index arrays are hop-invariant) ----
  auto build_pre = [&](const int* idx, int n, int nseg, int* cnt, int* off) {
    hipMemsetAsync(cnt, 0, (size_t)nseg * sizeof(int), stream);
    int nbh = (n + 255) / 256;
    hist_kernel<<<nbh, 256, 0, stream>>>(idx, cnt, n);
    int nbs = (nseg + 255) / 256;
    scan_block<<<nbs, 256, 0, stream>>>(cnt, off, bsum, nseg);
    scan_top<<<1, 1024, 0, stream>>>(bsum, nbs);
    scan_add<<<nbs, 256, 0, stream>>>(off, bsum, nseg, n);
    hipMemcpyAsync(cnt, off, (size_t)nseg * sizeof(int),
                   hipMemcpyDeviceToDevice, stream);  // cursor = offsets
  };

  build_pre(head, n_edges, N_ENT, c_head, o_head);
  fill_csr_packed<<<(n_edges + 255) / 256, 256, 0, stream>>>(
      head, tail, etype, c_head, pk_head, n_edges);

  build_pre(mcol, n_inter, N_ITEMS, c_col, o_col);
  fill_csr_val<<<(n_inter + 255) / 256, 256, 0, stream>>>(
      mcol, mrow, c_col, vr_col, n_inter);

  build_pre(mrow, n_inter, N_USERS, c_row, o_row);
  fill_csr_val<<<(n_inter + 255) / 256, 256, 0, stream>>>(
      mrow, mcol, c_row, vc_row, n_inter);

  const float* cur_ent = ent_emb;
  const float* cur_usr = user_emb;

  for (int i = 0; i < n_hops; ++i) {
    float* ea = (i & 1) ? entB : entA;

    kg_gather<<<(N_ENT + 3) / 4, 256, 0, stream>>>(
        cur_ent, relw, o_head, pk_head, ea, out_ent);

    inter_gather<<<(N_ITEMS + 3) / 4, 256, 0, stream>>>(
        cur_usr, relw, o_col, vr_col, iu);

    fuse_items<<<(N_ITEMS + 3) / 4, 256, 0, stream>>>(
        ea, iu, g1 + (size_t)i * D * D, g2 + (size_t)i * D * D, out_ent);

    user_gather<<<(N_USERS + 3) / 4, 256, 0, stream>>>(
        iu, o_row, vc_row, usr, out_usr);

    cur_ent = ea;
    cur_usr = usr;
  }
}

// Round 4
// 1037.503 us; speedup vs baseline: 2.0728x; 1.0152x over previous
//
#include <hip/hip_runtime.h>
#include <hip/hip_bf16.h>

#define D 64
#define N_USERS 100000
#define N_ITEMS 50000
#define N_ENT   200000
#define EPS 1e-12f

typedef unsigned short u16;

__device__ __forceinline__ float bf2f(u16 u) {
  return __uint_as_float(((unsigned)u) << 16);
}
__device__ __forceinline__ u16 f2bf(float f) {
  unsigned u = __float_as_uint(f);
  unsigned r = (u + 0x7FFFu + ((u >> 16) & 1u)) >> 16;  // RNE
  return (u16)r;
}

__device__ __forceinline__ float wave_rsqnorm(float v) {
  float ss = v * v;
#pragma unroll
  for (int m = 1; m < 64; m <<= 1) ss += __shfl_xor(ss, m);
  return 1.f / fmaxf(sqrtf(ss), EPS);
}

// ============================ init ==========================================
// residual init (f32 into d_out) + bf16 table conversion, one pass.
__global__ __launch_bounds__(256) void init_embed(
    const float* __restrict__ ent, const float* __restrict__ usr,
    float* __restrict__ out_ent, float* __restrict__ out_usr,
    u16* __restrict__ ent_bf, u16* __restrict__ usr_bf) {
  int i = blockIdx.x * 256 + threadIdx.x;
  if (i < N_ENT * D) {
    float v = ent[i];
    out_ent[i] = v;
    ent_bf[i] = f2bf(v);
  }
  if (i < N_USERS * D) {
    float v = usr[i];
    out_usr[i] = v;
    usr_bf[i] = f2bf(v);
  }
}

// ============================ CSR build =====================================
__global__ __launch_bounds__(256) void hist_all(
    const int* __restrict__ head, int n_edges,
    const int* __restrict__ mcol, const int* __restrict__ mrow, int n_inter,
    int* __restrict__ c_head, int* __restrict__ c_col, int* __restrict__ c_row) {
  int i = blockIdx.x * 256 + threadIdx.x;
  if (i < n_edges) atomicAdd(&c_head[head[i]], 1);
  if (i < n_inter) {
    atomicAdd(&c_col[mcol[i]], 1);
    atomicAdd(&c_row[mrow[i]], 1);
  }
}

// 256-elem scan per block -> exclusive out + block total
__global__ __launch_bounds__(256) void scan_block(
    const int* __restrict__ in, int* __restrict__ out,
    int* __restrict__ bsum, int n) {
  __shared__ int sm[256];
  int tid = threadIdx.x;
  int i = blockIdx.x * 256 + tid;
  int v = (i < n) ? in[i] : 0;
  sm[tid] = v;
  __syncthreads();
  for (int ofs = 1; ofs < 256; ofs <<= 1) {
    int t = (tid >= ofs) ? sm[tid - ofs] : 0;
    __syncthreads();
    sm[tid] += t;
    __syncthreads();
  }
  if (i < n) out[i] = sm[tid] - v;  // exclusive
  if (tid == 255) bsum[blockIdx.x] = sm[255];
}

__global__ __launch_bounds__(1024) void scan_top(int* __restrict__ bsum, int nb) {
  __shared__ int sm[1024];
  int tid = threadIdx.x;
  int v = (tid < nb) ? bsum[tid] : 0;
  sm[tid] = v;
  __syncthreads();
  for (int ofs = 1; ofs < 1024; ofs <<= 1) {
    int t = (tid >= ofs) ? sm[tid - ofs] : 0;
    __syncthreads();
    sm[tid] += t;
    __syncthreads();
  }
  if (tid < nb) bsum[tid] = sm[tid] - v;  // exclusive
}

// finalize offsets AND write the atomic cursor copy (saves a d2d memcpy)
__global__ __launch_bounds__(256) void scan_add(
    int* __restrict__ out, int* __restrict__ cur,
    const int* __restrict__ bsum, int n, int total) {
  int i = blockIdx.x * 256 + threadIdx.x;
  if (i < n) {
    int v = out[i] + bsum[blockIdx.x];
    out[i] = v;
    cur[i] = v;
  }
  if (i == 0) out[n] = total;  // tail sentinel
}

// head CSR: store packed (tail | etype<<24)
__global__ __launch_bounds__(256) void fill_csr_packed(
    const int* __restrict__ idx, const int* __restrict__ tail,
    const int* __restrict__ etype, int* __restrict__ cur,
    int* __restrict__ vals, int n) {
  int i = blockIdx.x * 256 + threadIdx.x;
  if (i < n) {
    int p = atomicAdd(&cur[idx[i]], 1);
    vals[p] = tail[i] | (etype[i] << 24);
  }
}

// both interaction CSRs in one pass
__global__ __launch_bounds__(256) void fill_inter(
    const int* __restrict__ mrow, const int* __restrict__ mcol,
    int* __restrict__ c_col, int* __restrict__ c_row,
    int* __restrict__ vr_col, int* __restrict__ vc_row, int n) {
  int i = blockIdx.x * 256 + threadIdx.x;
  if (i < n) {
    int r = mrow[i], c = mcol[i];
    int p = atomicAdd(&c_col[c], 1);
    vr_col[p] = r;
    int q = atomicAdd(&c_row[r], 1);
    vc_row[q] = c;
  }
}

// ==================== pipelined bf16 segment-sum helpers ====================
__device__ __forceinline__ float segsum_idx_bf(
    const int* __restrict__ il, int b, int e, int lane,
    const u16* __restrict__ tab) {
  float acc = 0.f;
  for (int j0 = b; j0 < e; j0 += 64) {
    int cnt = min(64, e - j0);
    int p = (j0 + lane < e) ? il[j0 + lane] : 0;
    int jj = 0;
    for (; jj + 8 <= cnt; jj += 8) {
      u16 uv[8];
#pragma unroll
      for (int k = 0; k < 8; ++k) {
        int q = __shfl(p, jj + k);
        uv[k] = tab[q * D + lane];
      }
#pragma unroll
      for (int k = 0; k < 8; ++k) acc += bf2f(uv[k]);
    }
    for (; jj < cnt; ++jj) acc += bf2f(tab[__shfl(p, jj) * D + lane]);
  }
  return acc;
}

// ============================ per-hop kernels ===============================
__global__ __launch_bounds__(256) void kg_gather(
    const u16* __restrict__ ent, const float* __restrict__ relw,
    const int* __restrict__ off, const int* __restrict__ pk,
    float* __restrict__ ea_items, u16* __restrict__ ent_next,
    float* __restrict__ res) {
  int h = blockIdx.x * 4 + (threadIdx.x >> 6);
  if (h >= N_ENT) return;
  int lane = threadIdx.x & 63;
  int b = off[h], e = off[h + 1];
  float acc = 0.f;
  for (int j0 = b; j0 < e; j0 += 64) {
    int cnt = min(64, e - j0);
    int p = (j0 + lane < e) ? pk[j0 + lane] : 0;
    int jj = 0;
    for (; jj + 8 <= cnt; jj += 8) {
      u16 uv[8];
      float rw[8];
#pragma unroll
      for (int k = 0; k < 8; ++k) {
        int q = __shfl(p, jj + k);
        uv[k] = ent[(q & 0xFFFFFF) * D + lane];
        rw[k] = relw[(((unsigned)q) >> 24) * D + lane];
      }
#pragma unroll
      for (int k = 0; k < 8; ++k) acc += bf2f(uv[k]) * rw[k];
    }
    for (; jj < cnt; ++jj) {
      int q = __shfl(p, jj);
      acc += bf2f(ent[(q & 0xFFFFFF) * D + lane]) *
             relw[(((unsigned)q) >> 24) * D + lane];
    }
  }
  int o = h * D + lane;
  if (h < N_ITEMS) {
    ea_items[o] = acc;  // raw f32: fuse_items consumes this
  } else {
    float nv = acc * wave_rsqnorm(acc);
    ent_next[o] = f2bf(nv);
    res[o] += nv;
  }
}

__global__ __launch_bounds__(256) void inter_gather(
    const u16* __restrict__ usr_bf, const float* __restrict__ relw,
    const int* __restrict__ off, const int* __restrict__ vr,
    float* __restrict__ iu) {
  int c = blockIdx.x * 4 + (threadIdx.x >> 6);
  if (c >= N_ITEMS) return;
  int lane = threadIdx.x & 63;
  int b = off[c], e = off[c + 1];
  float acc = segsum_idx_bf(vr, b, e, lane, usr_bf);
  iu[c * D + lane] = acc * relw[lane];
}

// gate GEMM + fusion; raw fusion -> fus_bf (bf16), normalized -> ent_next
// item region (bf16) + f32 residual.
__global__ __launch_bounds__(256) void fuse_items(
    const float* __restrict__ ea_items, const float* __restrict__ iu,
    const float* __restrict__ g1, const float* __restrict__ g2,
    u16* __restrict__ fus_bf, u16* __restrict__ ent_next,
    float* __restrict__ res) {
  __shared__ float G1[D][D + 1];
  __shared__ float G2[D][D + 1];
  for (int i = threadIdx.x; i < D * D; i += 256) {
    G1[i >> 6][i & 63] = g1[i];
    G2[i >> 6][i & 63] = g2[i];
  }
  __syncthreads();
  int row = blockIdx.x * 4 + (threadIdx.x >> 6);
  if (row >= N_ITEMS) return;
  int lane = threadIdx.x & 63;
  int o = row * D + lane;
  float eav = ea_items[o];
  float uv = iu[o];
  float s = 0.f;
#pragma unroll 8
  for (int k = 0; k < D; ++k) {
    s += __shfl(eav, k) * G1[lane][k] + __shfl(uv, k) * G2[lane][k];
  }
  float gi = s > 0.f ? s : 0.2f * s;
  float fus = gi * eav + (1.f - gi) * uv;
  fus_bf[o] = f2bf(fus);  // raw fusion (user_gather input)
  float nv = fus * wave_rsqnorm(fus);
  ent_next[o] = f2bf(nv);
  res[o] += nv;
}

__global__ __launch_bounds__(256) void user_gather(
    const u16* __restrict__ fus_bf, const int* __restrict__ off,
    const int* __restrict__ vc, u16* __restrict__ usr_bf,
    float* __restrict__ res) {
  int u = blockIdx.x * 4 + (threadIdx.x >> 6);
  if (u >= N_USERS) return;
  int lane = threadIdx.x & 63;
  int b = off[u], e = off[u + 1];
  float acc = segsum_idx_bf(vc, b, e, lane, fus_bf);
  float nv = acc * wave_rsqnorm(acc);
  int o = u * D + lane;
  usr_bf[o] = f2bf(nv);
  res[o] += nv;
}

// ============================ launch ========================================
extern "C" void kernel_launch(void* const* d_in, const int* in_sizes, int n_in,
                              void* d_out, int out_size, void* d_ws, size_t ws_size,
                              hipStream_t stream) {
  const float* user_emb = (const float*)d_in[0];
  const float* ent_emb  = (const float*)d_in[1];
  const float* relw     = (const float*)d_in[2];
  const float* g1       = (const float*)d_in[3];
  const float* g2       = (const float*)d_in[4];
  const int*   head     = (const int*)d_in[5];
  const int*   tail     = (const int*)d_in[6];
  const int*   etype    = (const int*)d_in[7];
  const int*   mrow     = (const int*)d_in[8];
  const int*   mcol     = (const int*)d_in[9];

  const int n_edges = in_sizes[5];
  const int n_inter = in_sizes[8];
  const int n_hops  = in_sizes[3] / (D * D);

  // ---- workspace carve: bf16 tables, f32 temps, then ints ----
  u16* entA_bf = (u16*)d_ws;
  u16* entB_bf = entA_bf + (size_t)N_ENT * D;
  u16* usr_bf  = entB_bf + (size_t)N_ENT * D;
  u16* fus_bf  = usr_bf + (size_t)N_USERS * D;
  float* ea_items = (float*)(fus_bf + (size_t)N_ITEMS * D);
  float* iu       = ea_items + (size_t)N_ITEMS * D;
  int* ip = (int*)(iu + (size_t)N_ITEMS * D);
  int* c_head = ip;   ip += N_ENT;     // contiguous counters ->
  int* c_col  = ip;   ip += N_ITEMS;   //   one memset covers all three
  int* c_row  = ip;   ip += N_USERS;
  int* o_head = ip;   ip += N_ENT + 1;
  int* o_col  = ip;   ip += N_ITEMS + 1;
  int* o_row  = ip;   ip += N_USERS + 1;
  int* pk_head = ip;  ip += n_edges;   // packed tail|etype<<24
  int* vr_col  = ip;  ip += n_inter;   // mrow permuted by col
  int* vc_row  = ip;  ip += n_inter;   // mcol permuted by row
  int* bsum    = ip;  ip += 1024;

  float* out_ent = (float*)d_out;
  float* out_usr = out_ent + (size_t)N_ENT * D;

  init_embed<<<(N_ENT * D + 255) / 256, 256, 0, stream>>>(
      ent_emb, user_emb, out_ent, out_usr, entA_bf, usr_bf);

  hipMemsetAsync(c_head, 0, (size_t)(N_ENT + N_ITEMS + N_USERS) * sizeof(int),
                 stream);
  hist_all<<<(n_edges + 255) / 256, 256, 0, stream>>>(
      head, n_edges, mcol, mrow, n_inter, c_head, c_col, c_row);

  auto scan3 = [&](int* cnt, int* off, int nseg, int total) {
    int nbs = (nseg + 255) / 256;
    scan_block<<<nbs, 256, 0, stream>>>(cnt, off, bsum, nseg);
    scan_top<<<1, 1024, 0, stream>>>(bsum, nbs);
    scan_add<<<nbs, 256, 0, stream>>>(off, cnt, bsum, nseg, total);
  };
  scan3(c_head, o_head, N_ENT, n_edges);
  scan3(c_col, o_col, N_ITEMS, n_inter);
  scan3(c_row, o_row, N_USERS, n_inter);

  fill_csr_packed<<<(n_edges + 255) / 256, 256, 0, stream>>>(
      head, tail, etype, c_head, pk_head, n_edges);
  fill_inter<<<(n_inter + 255) / 256, 256, 0, stream>>>(
      mrow, mcol, c_col, c_row, vr_col, vc_row, n_inter);

  for (int i = 0; i < n_hops; ++i) {
    const u16* ecur = (i & 1) ? entB_bf : entA_bf;
    u16* enxt       = (i & 1) ? entA_bf : entB_bf;

    kg_gather<<<(N_ENT + 3) / 4, 256, 0, stream>>>(
        ecur, relw, o_head, pk_head, ea_items, enxt, out_ent);

    inter_gather<<<(N_ITEMS + 3) / 4, 256, 0, stream>>>(
        usr_bf, relw, o_col, vr_col, iu);

    fuse_items<<<(N_ITEMS + 3) / 4, 256, 0, stream>>>(
        ea_items, iu, g1 + (size_t)i * D * D, g2 + (size_t)i * D * D,
        fus_bf, enxt, out_ent);

    user_gather<<<(N_USERS + 3) / 4, 256, 0, stream>>>(
        fus_bf, o_row, vc_row, usr_bf, out_usr);
  }
}

// Round 5
// 716.722 us; speedup vs baseline: 3.0005x; 1.4476x over previous
//
#include <hip/hip_runtime.h>
#include <hip/hip_bf16.h>

#define D 64
#define N_USERS 100000
#define N_ITEMS 50000
#define N_ENT   200000
#define EPS 1e-12f
#define CHUNK 4096
#define NBINP 512   // padded bin/segment-counter array size
#define CAP   8192  // max edges per bin for LDS-staged pass 2

typedef unsigned short u16;

template<int MODE> struct Cfg;
template<> struct Cfg<0> { static constexpr int SHIFT = 9; static constexpr int NSEG = N_ENT;   };
template<> struct Cfg<1> { static constexpr int SHIFT = 7; static constexpr int NSEG = N_ITEMS; };
template<> struct Cfg<2> { static constexpr int SHIFT = 8; static constexpr int NSEG = N_USERS; };
template<int MODE> constexpr int nbin_of() {
  return (Cfg<MODE>::NSEG + (1 << Cfg<MODE>::SHIFT) - 1) >> Cfg<MODE>::SHIFT;  // = 391 all modes
}

__device__ __forceinline__ float bf2f(u16 u) {
  return __uint_as_float(((unsigned)u) << 16);
}
__device__ __forceinline__ u16 f2bf(float f) {
  unsigned u = __float_as_uint(f);
  unsigned r = (u + 0x7FFFu + ((u >> 16) & 1u)) >> 16;  // RNE
  return (u16)r;
}
__device__ __forceinline__ float wave_rsqnorm(float v) {
  float ss = v * v;
#pragma unroll
  for (int m = 1; m < 64; m <<= 1) ss += __shfl_xor(ss, m);
  return 1.f / fmaxf(sqrtf(ss), EPS);
}

// ============================ init ==========================================
__global__ __launch_bounds__(256) void init_embed(
    const float* __restrict__ ent, const float* __restrict__ usr,
    float* __restrict__ out_ent, float* __restrict__ out_usr,
    u16* __restrict__ ent_bf, u16* __restrict__ usr_bf) {
  int i = blockIdx.x * 256 + threadIdx.x;
  if (i < N_ENT * D) {
    float v = ent[i];
    out_ent[i] = v;
    ent_bf[i] = f2bf(v);
  }
  if (i < N_USERS * D) {
    float v = usr[i];
    out_usr[i] = v;
    usr_bf[i] = f2bf(v);
  }
}

// ======================= generic scan (for blockcnt) ========================
__global__ __launch_bounds__(256) void scan_block(
    const int* __restrict__ in, int* __restrict__ out,
    int* __restrict__ bsum, int n) {
  __shared__ int sm[256];
  int tid = threadIdx.x;
  int i = blockIdx.x * 256 + tid;
  int v = (i < n) ? in[i] : 0;
  sm[tid] = v;
  __syncthreads();
  for (int ofs = 1; ofs < 256; ofs <<= 1) {
    int t = (tid >= ofs) ? sm[tid - ofs] : 0;
    __syncthreads();
    sm[tid] += t;
    __syncthreads();
  }
  if (i < n) out[i] = sm[tid] - v;  // exclusive
  if (tid == 255) bsum[blockIdx.x] = sm[255];
}

__global__ __launch_bounds__(1024) void scan_top(int* __restrict__ bsum, int nb) {
  __shared__ int sm[1024];
  int tid = threadIdx.x;
  int v = (tid < nb) ? bsum[tid] : 0;
  sm[tid] = v;
  __syncthreads();
  for (int ofs = 1; ofs < 1024; ofs <<= 1) {
    int t = (tid >= ofs) ? sm[tid - ofs] : 0;
    __syncthreads();
    sm[tid] += t;
    __syncthreads();
  }
  if (tid < nb) bsum[tid] = sm[tid] - v;  // exclusive
}

__global__ __launch_bounds__(256) void scan_addv(
    int* __restrict__ out, const int* __restrict__ bsum, int n) {
  int i = blockIdx.x * 256 + threadIdx.x;
  if (i < n) out[i] += bsum[blockIdx.x];
}

// =================== pass 1: bin histogram + binned scatter =================
template<int MODE>
__global__ __launch_bounds__(256) void p1_hist(
    const int* __restrict__ keys, int n, int* __restrict__ bc, int nblk) {
  constexpr int SHIFT = Cfg<MODE>::SHIFT;
  constexpr int NBIN = nbin_of<MODE>();
  __shared__ int h[NBINP];
  int tid = threadIdx.x;
  h[tid] = 0; h[tid + 256] = 0;
  __syncthreads();
  int base = blockIdx.x * CHUNK;
  int end = min(base + CHUNK, n);
  for (int i = base + tid; i < end; i += 256)
    atomicAdd(&h[keys[i] >> SHIFT], 1);
  __syncthreads();
  for (int b = tid; b < NBIN; b += 256)
    bc[b * nblk + blockIdx.x] = h[b];
}

template<int MODE>
__global__ __launch_bounds__(256) void p1_scatter(
    const int* __restrict__ keys, const int* __restrict__ pa,
    const int* __restrict__ pb, int n, const int* __restrict__ sbc, int nblk,
    int2* __restrict__ out) {
  constexpr int SHIFT = Cfg<MODE>::SHIFT;
  constexpr int NBIN = nbin_of<MODE>();
  __shared__ int h[NBINP];
  __shared__ int cur[NBINP];
  __shared__ int bb[NBINP];
  __shared__ int2 staged[CHUNK];
  __shared__ int dstA[CHUNK];
  int tid = threadIdx.x;
  h[tid] = 0; h[tid + 256] = 0;
  __syncthreads();
  int base = blockIdx.x * CHUNK;
  int end = min(base + CHUNK, n);
  for (int i = base + tid; i < end; i += 256)
    atomicAdd(&h[keys[i] >> SHIFT], 1);
  __syncthreads();
  int o0 = h[tid], o1 = h[tid + 256];
  // inclusive Hillis-Steele over 512 (reads pre-barrier, writes post-barrier)
  for (int ofs = 1; ofs < NBINP; ofs <<= 1) {
    int v0 = (tid >= ofs) ? h[tid - ofs] : 0;
    int v1 = (tid + 256 >= ofs) ? h[tid + 256 - ofs] : 0;
    __syncthreads();
    h[tid] += v0; h[tid + 256] += v1;
    __syncthreads();
  }
  int e0 = h[tid] - o0, e1 = h[tid + 256] - o1;  // exclusive
  cur[tid] = e0; cur[tid + 256] = e1;
  if (tid < NBIN)        bb[tid] = sbc[tid * nblk + blockIdx.x] - e0;
  if (tid + 256 < NBIN)  bb[tid + 256] = sbc[(tid + 256) * nblk + blockIdx.x] - e1;
  __syncthreads();
  for (int i = base + tid; i < end; i += 256) {
    int k = keys[i];
    int bin = k >> SHIFT;
    int payload;
    if constexpr (MODE == 0) payload = pa[i] | (pb[i] << 24);
    else                     payload = pa[i];
    int lp = atomicAdd(&cur[bin], 1);
    staged[lp] = make_int2(k, payload);
    dstA[lp] = bb[bin] + lp;
  }
  __syncthreads();
  int cnt = end - base;
  for (int t = tid; t < cnt; t += 256) out[dstA[t]] = staged[t];
}

// ============ pass 2: in-bin sort -> final payload array + offsets ==========
template<int MODE>
__global__ __launch_bounds__(256) void p2_sort(
    const int2* __restrict__ binned, const int* __restrict__ sbc, int nblk,
    int n, int* __restrict__ vals, int* __restrict__ off) {
  constexpr int SHIFT = Cfg<MODE>::SHIFT;
  constexpr int NSEG = Cfg<MODE>::NSEG;
  constexpr int SEGBIN = 1 << SHIFT;
  constexpr int NBIN = nbin_of<MODE>();
  __shared__ int h[NBINP];
  __shared__ int cur[NBINP];
  __shared__ int staged[CAP];
  int tid = threadIdx.x;
  int b = blockIdx.x;
  int start = sbc[b * nblk];
  int endp = (b == NBIN - 1) ? n : sbc[(b + 1) * nblk];
  int cnt = endp - start;
  h[tid] = 0; h[tid + 256] = 0;
  __syncthreads();
  int segbase = b << SHIFT;
  for (int t = tid; t < cnt; t += 256)
    atomicAdd(&h[binned[start + t].x - segbase], 1);
  __syncthreads();
  int o0 = h[tid], o1 = h[tid + 256];
  for (int ofs = 1; ofs < NBINP; ofs <<= 1) {
    int v0 = (tid >= ofs) ? h[tid - ofs] : 0;
    int v1 = (tid + 256 >= ofs) ? h[tid + 256 - ofs] : 0;
    __syncthreads();
    h[tid] += v0; h[tid + 256] += v1;
    __syncthreads();
  }
  int e0 = h[tid] - o0, e1 = h[tid + 256] - o1;
  // segment offsets (coalesced)
  if (tid < SEGBIN && segbase + tid < NSEG) off[segbase + tid] = start + e0;
  if (tid + 256 < SEGBIN && segbase + tid + 256 < NSEG)
    off[segbase + tid + 256] = start + e1;
  if (b == NBIN - 1 && tid == 0) off[NSEG] = n;  // sentinel
  cur[tid] = e0; cur[tid + 256] = e1;
  __syncthreads();
  if (cnt <= CAP) {
    for (int t = tid; t < cnt; t += 256) {
      int2 e = binned[start + t];
      int lp = atomicAdd(&cur[e.x - segbase], 1);
      staged[lp] = e.y;
    }
    __syncthreads();
    for (int t = tid; t < cnt; t += 256) vals[start + t] = staged[t];
  } else {  // overflow fallback: correct, scattered
    for (int t = tid; t < cnt; t += 256) {
      int2 e = binned[start + t];
      int lp = atomicAdd(&cur[e.x - segbase], 1);
      vals[start + lp] = e.y;
    }
  }
}

// ============================ per-hop kernels ===============================
__global__ __launch_bounds__(256) void kg_gather(
    const u16* __restrict__ ent, const float* __restrict__ relw,
    const int* __restrict__ off, const int* __restrict__ pk,
    float* __restrict__ ea_items, u16* __restrict__ ent_next,
    float* __restrict__ res) {
  int h = blockIdx.x * 4 + (threadIdx.x >> 6);
  if (h >= N_ENT) return;
  int lane = threadIdx.x & 63;
  int b = off[h], e = off[h + 1];
  float acc = 0.f;
  for (int j0 = b; j0 < e; j0 += 64) {
    int cnt = min(64, e - j0);
    int p = (j0 + lane < e) ? pk[j0 + lane] : 0;
    int jj = 0;
    for (; jj + 8 <= cnt; jj += 8) {
      u16 uv[8];
      float rw[8];
#pragma unroll
      for (int k = 0; k < 8; ++k) {
        int q = __shfl(p, jj + k);
        uv[k] = ent[(q & 0xFFFFFF) * D + lane];
        rw[k] = relw[(((unsigned)q) >> 24) * D + lane];
      }
#pragma unroll
      for (int k = 0; k < 8; ++k) acc += bf2f(uv[k]) * rw[k];
    }
    for (; jj < cnt; ++jj) {
      int q = __shfl(p, jj);
      acc += bf2f(ent[(q & 0xFFFFFF) * D + lane]) *
             relw[(((unsigned)q) >> 24) * D + lane];
    }
  }
  int o = h * D + lane;
  if (h < N_ITEMS) {
    ea_items[o] = acc;  // raw f32: fuse_items consumes this
  } else {
    float nv = acc * wave_rsqnorm(acc);
    ent_next[o] = f2bf(nv);
    res[o] += nv;
  }
}

__device__ __forceinline__ float segsum_idx_bf(
    const int* __restrict__ il, int b, int e, int lane,
    const u16* __restrict__ tab) {
  float acc = 0.f;
  for (int j0 = b; j0 < e; j0 += 64) {
    int cnt = min(64, e - j0);
    int p = (j0 + lane < e) ? il[j0 + lane] : 0;
    int jj = 0;
    for (; jj + 8 <= cnt; jj += 8) {
      u16 uv[8];
#pragma unroll
      for (int k = 0; k < 8; ++k) {
        int q = __shfl(p, jj + k);
        uv[k] = tab[q * D + lane];
      }
#pragma unroll
      for (int k = 0; k < 8; ++k) acc += bf2f(uv[k]);
    }
    for (; jj < cnt; ++jj) acc += bf2f(tab[__shfl(p, jj) * D + lane]);
  }
  return acc;
}

__global__ __launch_bounds__(256) void inter_gather(
    const u16* __restrict__ usr_bf, const float* __restrict__ relw,
    const int* __restrict__ off, const int* __restrict__ vr,
    float* __restrict__ iu) {
  int c = blockIdx.x * 4 + (threadIdx.x >> 6);
  if (c >= N_ITEMS) return;
  int lane = threadIdx.x & 63;
  int b = off[c], e = off[c + 1];
  float acc = segsum_idx_bf(vr, b, e, lane, usr_bf);
  iu[c * D + lane] = acc * relw[lane];
}

__global__ __launch_bounds__(256) void fuse_items(
    const float* __restrict__ ea_items, const float* __restrict__ iu,
    const float* __restrict__ g1, const float* __restrict__ g2,
    u16* __restrict__ fus_bf, u16* __restrict__ ent_next,
    float* __restrict__ res) {
  __shared__ float G1[D][D + 1];
  __shared__ float G2[D][D + 1];
  for (int i = threadIdx.x; i < D * D; i += 256) {
    G1[i >> 6][i & 63] = g1[i];
    G2[i >> 6][i & 63] = g2[i];
  }
  __syncthreads();
  int row = blockIdx.x * 4 + (threadIdx.x >> 6);
  if (row >= N_ITEMS) return;
  int lane = threadIdx.x & 63;
  int o = row * D + lane;
  float eav = ea_items[o];
  float uv = iu[o];
  float s = 0.f;
#pragma unroll 8
  for (int k = 0; k < D; ++k) {
    s += __shfl(eav, k) * G1[lane][k] + __shfl(uv, k) * G2[lane][k];
  }
  float gi = s > 0.f ? s : 0.2f * s;
  float fus = gi * eav + (1.f - gi) * uv;
  fus_bf[o] = f2bf(fus);  // raw fusion (user_gather input)
  float nv = fus * wave_rsqnorm(fus);
  ent_next[o] = f2bf(nv);
  res[o] += nv;
}

__global__ __launch_bounds__(256) void user_gather(
    const u16* __restrict__ fus_bf, const int* __restrict__ off,
    const int* __restrict__ vc, u16* __restrict__ usr_bf,
    float* __restrict__ res) {
  int u = blockIdx.x * 4 + (threadIdx.x >> 6);
  if (u >= N_USERS) return;
  int lane = threadIdx.x & 63;
  int b = off[u], e = off[u + 1];
  float acc = segsum_idx_bf(vc, b, e, lane, fus_bf);
  float nv = acc * wave_rsqnorm(acc);
  int o = u * D + lane;
  usr_bf[o] = f2bf(nv);
  res[o] += nv;
}

// ============================ sort driver ===================================
template<int MODE>
static void run_sort(const int* keys, const int* pa, const int* pb, int n,
                     int2* binned, int* vals, int* off, int* bc, int* bsum,
                     hipStream_t stream) {
  constexpr int NBIN = nbin_of<MODE>();
  int nblk = (n + CHUNK - 1) / CHUNK;
  int len = NBIN * nblk;
  p1_hist<MODE><<<nblk, 256, 0, stream>>>(keys, n, bc, nblk);
  int nbs = (len + 255) / 256;
  scan_block<<<nbs, 256, 0, stream>>>(bc, bc, bsum, len);
  scan_top<<<1, 1024, 0, stream>>>(bsum, nbs);
  scan_addv<<<nbs, 256, 0, stream>>>(bc, bsum, len);
  p1_scatter<MODE><<<nblk, 256, 0, stream>>>(keys, pa, pb, n, bc, nblk, binned);
  p2_sort<MODE><<<NBIN, 256, 0, stream>>>(binned, bc, nblk, n, vals, off);
}

// ============================ launch ========================================
extern "C" void kernel_launch(void* const* d_in, const int* in_sizes, int n_in,
                              void* d_out, int out_size, void* d_ws, size_t ws_size,
                              hipStream_t stream) {
  const float* user_emb = (const float*)d_in[0];
  const float* ent_emb  = (const float*)d_in[1];
  const float* relw     = (const float*)d_in[2];
  const float* g1       = (const float*)d_in[3];
  const float* g2       = (const float*)d_in[4];
  const int*   head     = (const int*)d_in[5];
  const int*   tail     = (const int*)d_in[6];
  const int*   etype    = (const int*)d_in[7];
  const int*   mrow     = (const int*)d_in[8];
  const int*   mcol     = (const int*)d_in[9];

  const int n_edges = in_sizes[5];
  const int n_inter = in_sizes[8];
  const int n_hops  = in_sizes[3] / (D * D);

  // ---- workspace carve ----
  u16* entA_bf = (u16*)d_ws;
  u16* entB_bf = entA_bf + (size_t)N_ENT * D;
  u16* usr_bf  = entB_bf + (size_t)N_ENT * D;
  u16* fus_bf  = usr_bf + (size_t)N_USERS * D;
  float* ea_items = (float*)(fus_bf + (size_t)N_ITEMS * D);
  float* iu       = ea_items + (size_t)N_ITEMS * D;
  int* ip = (int*)(iu + (size_t)N_ITEMS * D);
  int* o_head = ip;   ip += N_ENT + 1;
  int* o_col  = ip;   ip += N_ITEMS + 1;
  int* o_row  = ip;   ip += N_USERS + 1;
  int* pk_head = ip;  ip += n_edges;   // packed tail|etype<<24, grouped by head
  int* vr_col  = ip;  ip += n_inter;   // mrow grouped by col
  int* vc_row  = ip;  ip += n_inter;   // mcol grouped by row
  int* bc      = ip;  ip += 391 * ((n_edges + CHUNK - 1) / CHUNK) + 1;  // blockcnt (max)
  int* bsum    = ip;  ip += 1024;

  float* out_ent = (float*)d_out;
  float* out_usr = out_ent + (size_t)N_ENT * D;

  // ---- sort temps live in d_out (overwritten by init_embed afterwards) ----
  int2* bin_head = (int2*)d_out;
  int2* bin_col  = bin_head + n_edges;
  int2* bin_row  = bin_col + n_inter;

  run_sort<0>(head, tail, etype, n_edges, bin_head, pk_head, o_head, bc, bsum, stream);
  run_sort<1>(mcol, mrow, nullptr, n_inter, bin_col, vr_col, o_col, bc, bsum, stream);
  run_sort<2>(mrow, mcol, nullptr, n_inter, bin_row, vc_row, o_row, bc, bsum, stream);

  // residual init AFTER sorting (d_out was scratch until here)
  init_embed<<<(N_ENT * D + 255) / 256, 256, 0, stream>>>(
      ent_emb, user_emb, out_ent, out_usr, entA_bf, usr_bf);

  for (int i = 0; i < n_hops; ++i) {
    const u16* ecur = (i & 1) ? entB_bf : entA_bf;
    u16* enxt       = (i & 1) ? entA_bf : entB_bf;

    kg_gather<<<(N_ENT + 3) / 4, 256, 0, stream>>>(
        ecur, relw, o_head, pk_head, ea_items, enxt, out_ent);

    inter_gather<<<(N_ITEMS + 3) / 4, 256, 0, stream>>>(
        usr_bf, relw, o_col, vr_col, iu);

    fuse_items<<<(N_ITEMS + 3) / 4, 256, 0, stream>>>(
        ea_items, iu, g1 + (size_t)i * D * D, g2 + (size_t)i * D * D,
        fus_bf, enxt, out_ent);

    user_gather<<<(N_USERS + 3) / 4, 256, 0, stream>>>(
        fus_bf, o_row, vc_row, usr_bf, out_usr);
  }
}

// Round 6
// 606.988 us; speedup vs baseline: 3.5430x; 1.1808x over previous
//
#include <hip/hip_runtime.h>
#include <hip/hip_bf16.h>

#define D 64
#define N_USERS 100000
#define N_ITEMS 50000
#define N_ENT   200000
#define EPS 1e-12f
#define CHUNK 4096
#define NBINP 512   // padded bin/segment-counter array size
#define CAP   8192  // max edges per bin for LDS-staged pass 2

typedef unsigned short u16;

template<int MODE> struct Cfg;
template<> struct Cfg<0> { static constexpr int SHIFT = 9; static constexpr int NSEG = N_ENT;   };
template<> struct Cfg<1> { static constexpr int SHIFT = 7; static constexpr int NSEG = N_ITEMS; };
template<> struct Cfg<2> { static constexpr int SHIFT = 8; static constexpr int NSEG = N_USERS; };
template<int MODE> constexpr int nbin_of() {
  return (Cfg<MODE>::NSEG + (1 << Cfg<MODE>::SHIFT) - 1) >> Cfg<MODE>::SHIFT;  // = 391 all modes
}

__device__ __forceinline__ float bf2f(u16 u) {
  return __uint_as_float(((unsigned)u) << 16);
}
__device__ __forceinline__ u16 f2bf(float f) {
  unsigned u = __float_as_uint(f);
  unsigned r = (u + 0x7FFFu + ((u >> 16) & 1u)) >> 16;  // RNE
  return (u16)r;
}
__device__ __forceinline__ float wave_rsqnorm(float v) {
  float ss = v * v;
#pragma unroll
  for (int m = 1; m < 64; m <<= 1) ss += __shfl_xor(ss, m);
  return 1.f / fmaxf(sqrtf(ss), EPS);
}
// lane-constant broadcast on the VALU (v_readlane), NOT the LDS pipe
__device__ __forceinline__ float bcast(float v, int k) {
  return __uint_as_float(__builtin_amdgcn_readlane(__float_as_uint(v), k));
}

// ============================ init ==========================================
__global__ __launch_bounds__(256) void init_embed(
    const float* __restrict__ ent, const float* __restrict__ usr,
    float* __restrict__ out_ent, float* __restrict__ out_usr,
    u16* __restrict__ ent_bf, u16* __restrict__ usr_bf) {
  int i = blockIdx.x * 256 + threadIdx.x;
  if (i < N_ENT * D) {
    float v = ent[i];
    out_ent[i] = v;
    ent_bf[i] = f2bf(v);
  }
  if (i < N_USERS * D) {
    float v = usr[i];
    out_usr[i] = v;
    usr_bf[i] = f2bf(v);
  }
}

// ======================= generic scan (for blockcnt) ========================
__global__ __launch_bounds__(256) void scan_block(
    const int* __restrict__ in, int* __restrict__ out,
    int* __restrict__ bsum, int n) {
  __shared__ int sm[256];
  int tid = threadIdx.x;
  int i = blockIdx.x * 256 + tid;
  int v = (i < n) ? in[i] : 0;
  sm[tid] = v;
  __syncthreads();
  for (int ofs = 1; ofs < 256; ofs <<= 1) {
    int t = (tid >= ofs) ? sm[tid - ofs] : 0;
    __syncthreads();
    sm[tid] += t;
    __syncthreads();
  }
  if (i < n) out[i] = sm[tid] - v;  // exclusive
  if (tid == 255) bsum[blockIdx.x] = sm[255];
}

__global__ __launch_bounds__(1024) void scan_top(int* __restrict__ bsum, int nb) {
  __shared__ int sm[1024];
  int tid = threadIdx.x;
  int v = (tid < nb) ? bsum[tid] : 0;
  sm[tid] = v;
  __syncthreads();
  for (int ofs = 1; ofs < 1024; ofs <<= 1) {
    int t = (tid >= ofs) ? sm[tid - ofs] : 0;
    __syncthreads();
    sm[tid] += t;
    __syncthreads();
  }
  if (tid < nb) bsum[tid] = sm[tid] - v;  // exclusive
}

__global__ __launch_bounds__(256) void scan_addv(
    int* __restrict__ out, const int* __restrict__ bsum, int n) {
  int i = blockIdx.x * 256 + threadIdx.x;
  if (i < n) out[i] += bsum[blockIdx.x];
}

// =================== pass 1: bin histogram + binned scatter =================
template<int MODE>
__global__ __launch_bounds__(256) void p1_hist(
    const int* __restrict__ keys, int n, int* __restrict__ bc, int nblk) {
  constexpr int SHIFT = Cfg<MODE>::SHIFT;
  constexpr int NBIN = nbin_of<MODE>();
  __shared__ int h[NBINP];
  int tid = threadIdx.x;
  h[tid] = 0; h[tid + 256] = 0;
  __syncthreads();
  int base = blockIdx.x * CHUNK;
  int end = min(base + CHUNK, n);
  for (int i = base + tid; i < end; i += 256)
    atomicAdd(&h[keys[i] >> SHIFT], 1);
  __syncthreads();
  for (int b = tid; b < NBIN; b += 256)
    bc[b * nblk + blockIdx.x] = h[b];
}

template<int MODE>
__global__ __launch_bounds__(256) void p1_scatter(
    const int* __restrict__ keys, const int* __restrict__ pa,
    const int* __restrict__ pb, int n, const int* __restrict__ sbc, int nblk,
    int2* __restrict__ out) {
  constexpr int SHIFT = Cfg<MODE>::SHIFT;
  constexpr int NBIN = nbin_of<MODE>();
  __shared__ int h[NBINP];
  __shared__ int cur[NBINP];
  __shared__ int bb[NBINP];
  __shared__ int2 staged[CHUNK];
  __shared__ int dstA[CHUNK];
  int tid = threadIdx.x;
  h[tid] = 0; h[tid + 256] = 0;
  __syncthreads();
  int base = blockIdx.x * CHUNK;
  int end = min(base + CHUNK, n);
  for (int i = base + tid; i < end; i += 256)
    atomicAdd(&h[keys[i] >> SHIFT], 1);
  __syncthreads();
  int o0 = h[tid], o1 = h[tid + 256];
  // inclusive Hillis-Steele over 512 (reads pre-barrier, writes post-barrier)
  for (int ofs = 1; ofs < NBINP; ofs <<= 1) {
    int v0 = (tid >= ofs) ? h[tid - ofs] : 0;
    int v1 = (tid + 256 >= ofs) ? h[tid + 256 - ofs] : 0;
    __syncthreads();
    h[tid] += v0; h[tid + 256] += v1;
    __syncthreads();
  }
  int e0 = h[tid] - o0, e1 = h[tid + 256] - o1;  // exclusive
  cur[tid] = e0; cur[tid + 256] = e1;
  if (tid < NBIN)        bb[tid] = sbc[tid * nblk + blockIdx.x] - e0;
  if (tid + 256 < NBIN)  bb[tid + 256] = sbc[(tid + 256) * nblk + blockIdx.x] - e1;
  __syncthreads();
  for (int i = base + tid; i < end; i += 256) {
    int k = keys[i];
    int bin = k >> SHIFT;
    int payload;
    if constexpr (MODE == 0) payload = pa[i] | (pb[i] << 24);
    else                     payload = pa[i];
    int lp = atomicAdd(&cur[bin], 1);
    staged[lp] = make_int2(k, payload);
    dstA[lp] = bb[bin] + lp;
  }
  __syncthreads();
  int cnt = end - base;
  for (int t = tid; t < cnt; t += 256) out[dstA[t]] = staged[t];
}

// ============ pass 2: in-bin sort -> final payload array + offsets ==========
template<int MODE>
__global__ __launch_bounds__(256) void p2_sort(
    const int2* __restrict__ binned, const int* __restrict__ sbc, int nblk,
    int n, int* __restrict__ vals, int* __restrict__ off) {
  constexpr int SHIFT = Cfg<MODE>::SHIFT;
  constexpr int NSEG = Cfg<MODE>::NSEG;
  constexpr int SEGBIN = 1 << SHIFT;
  constexpr int NBIN = nbin_of<MODE>();
  __shared__ int h[NBINP];
  __shared__ int cur[NBINP];
  __shared__ int staged[CAP];
  int tid = threadIdx.x;
  int b = blockIdx.x;
  int start = sbc[b * nblk];
  int endp = (b == NBIN - 1) ? n : sbc[(b + 1) * nblk];
  int cnt = endp - start;
  h[tid] = 0; h[tid + 256] = 0;
  __syncthreads();
  int segbase = b << SHIFT;
  for (int t = tid; t < cnt; t += 256)
    atomicAdd(&h[binned[start + t].x - segbase], 1);
  __syncthreads();
  int o0 = h[tid], o1 = h[tid + 256];
  for (int ofs = 1; ofs < NBINP; ofs <<= 1) {
    int v0 = (tid >= ofs) ? h[tid - ofs] : 0;
    int v1 = (tid + 256 >= ofs) ? h[tid + 256 - ofs] : 0;
    __syncthreads();
    h[tid] += v0; h[tid + 256] += v1;
    __syncthreads();
  }
  int e0 = h[tid] - o0, e1 = h[tid + 256] - o1;
  // segment offsets (coalesced)
  if (tid < SEGBIN && segbase + tid < NSEG) off[segbase + tid] = start + e0;
  if (tid + 256 < SEGBIN && segbase + tid + 256 < NSEG)
    off[segbase + tid + 256] = start + e1;
  if (b == NBIN - 1 && tid == 0) off[NSEG] = n;  // sentinel
  cur[tid] = e0; cur[tid + 256] = e1;
  __syncthreads();
  if (cnt <= CAP) {
    for (int t = tid; t < cnt; t += 256) {
      int2 e = binned[start + t];
      int lp = atomicAdd(&cur[e.x - segbase], 1);
      staged[lp] = e.y;
    }
    __syncthreads();
    for (int t = tid; t < cnt; t += 256) vals[start + t] = staged[t];
  } else {  // overflow fallback: correct, scattered
    for (int t = tid; t < cnt; t += 256) {
      int2 e = binned[start + t];
      int lp = atomicAdd(&cur[e.x - segbase], 1);
      vals[start + lp] = e.y;
    }
  }
}

// ============================ per-hop kernels ===============================
__global__ __launch_bounds__(256) void kg_gather(
    const u16* __restrict__ ent, const float* __restrict__ relw,
    const int* __restrict__ off, const int* __restrict__ pk,
    float* __restrict__ ea_items, u16* __restrict__ ent_next,
    float* __restrict__ res) {
  int h = blockIdx.x * 4 + (threadIdx.x >> 6);
  if (h >= N_ENT) return;
  int lane = threadIdx.x & 63;
  int b = off[h], e = off[h + 1];
  float acc = 0.f;
  for (int j0 = b; j0 < e; j0 += 64) {
    int cnt = min(64, e - j0);
    int p = (j0 + lane < e) ? pk[j0 + lane] : 0;
    int jj = 0;
    for (; jj + 8 <= cnt; jj += 8) {
      u16 uv[8];
      float rw[8];
#pragma unroll
      for (int k = 0; k < 8; ++k) {
        int q = __shfl(p, jj + k);
        uv[k] = ent[(q & 0xFFFFFF) * D + lane];
        rw[k] = relw[(((unsigned)q) >> 24) * D + lane];
      }
#pragma unroll
      for (int k = 0; k < 8; ++k) acc += bf2f(uv[k]) * rw[k];
    }
    for (; jj < cnt; ++jj) {
      int q = __shfl(p, jj);
      acc += bf2f(ent[(q & 0xFFFFFF) * D + lane]) *
             relw[(((unsigned)q) >> 24) * D + lane];
    }
  }
  int o = h * D + lane;
  if (h < N_ITEMS) {
    ea_items[o] = acc;  // raw f32: fuse_items consumes this
  } else {
    float nv = acc * wave_rsqnorm(acc);
    ent_next[o] = f2bf(nv);
    res[o] += nv;
  }
}

__device__ __forceinline__ float segsum_idx_bf(
    const int* __restrict__ il, int b, int e, int lane,
    const u16* __restrict__ tab) {
  float acc = 0.f;
  for (int j0 = b; j0 < e; j0 += 64) {
    int cnt = min(64, e - j0);
    int p = (j0 + lane < e) ? il[j0 + lane] : 0;
    int jj = 0;
    for (; jj + 8 <= cnt; jj += 8) {
      u16 uv[8];
#pragma unroll
      for (int k = 0; k < 8; ++k) {
        int q = __shfl(p, jj + k);
        uv[k] = tab[q * D + lane];
      }
#pragma unroll
      for (int k = 0; k < 8; ++k) acc += bf2f(uv[k]);
    }
    for (; jj < cnt; ++jj) acc += bf2f(tab[__shfl(p, jj) * D + lane]);
  }
  return acc;
}

__global__ __launch_bounds__(256) void inter_gather(
    const u16* __restrict__ usr_bf, const float* __restrict__ relw,
    const int* __restrict__ off, const int* __restrict__ vr,
    float* __restrict__ iu) {
  int c = blockIdx.x * 4 + (threadIdx.x >> 6);
  if (c >= N_ITEMS) return;
  int lane = threadIdx.x & 63;
  int b = off[c], e = off[c + 1];
  float acc = segsum_idx_bf(vr, b, e, lane, usr_bf);
  iu[c * D + lane] = acc * relw[lane];
}

// gate GEMM: G reads stay on the (conflict-free) LDS path, but the row
// broadcasts use v_readlane (VALU) instead of ds_bpermute -> LDS ops/k
// drop 4 -> 2. Two accumulators break the FMA dependence chain.
__global__ __launch_bounds__(256) void fuse_items(
    const float* __restrict__ ea_items, const float* __restrict__ iu,
    const float* __restrict__ g1, const float* __restrict__ g2,
    u16* __restrict__ fus_bf, u16* __restrict__ ent_next,
    float* __restrict__ res) {
  __shared__ float G1[D][D + 1];
  __shared__ float G2[D][D + 1];
  for (int i = threadIdx.x; i < D * D; i += 256) {
    G1[i >> 6][i & 63] = g1[i];
    G2[i >> 6][i & 63] = g2[i];
  }
  __syncthreads();
  int row = blockIdx.x * 4 + (threadIdx.x >> 6);
  if (row >= N_ITEMS) return;
  int lane = threadIdx.x & 63;
  int o = row * D + lane;
  float eav = ea_items[o];
  float uv = iu[o];
  float s1 = 0.f, s2 = 0.f;
#pragma unroll
  for (int k = 0; k < D; ++k) {
    s1 += bcast(eav, k) * G1[lane][k];
    s2 += bcast(uv, k) * G2[lane][k];
  }
  float s = s1 + s2;
  float gi = s > 0.f ? s : 0.2f * s;
  float fus = gi * eav + (1.f - gi) * uv;
  fus_bf[o] = f2bf(fus);  // raw fusion (user_gather input)
  float nv = fus * wave_rsqnorm(fus);
  ent_next[o] = f2bf(nv);
  res[o] += nv;
}

__global__ __launch_bounds__(256) void user_gather(
    const u16* __restrict__ fus_bf, const int* __restrict__ off,
    const int* __restrict__ vc, u16* __restrict__ usr_bf,
    float* __restrict__ res) {
  int u = blockIdx.x * 4 + (threadIdx.x >> 6);
  if (u >= N_USERS) return;
  int lane = threadIdx.x & 63;
  int b = off[u], e = off[u + 1];
  float acc = segsum_idx_bf(vc, b, e, lane, fus_bf);
  float nv = acc * wave_rsqnorm(acc);
  int o = u * D + lane;
  usr_bf[o] = f2bf(nv);
  res[o] += nv;
}

// ============================ sort driver ===================================
template<int MODE>
static void run_sort(const int* keys, const int* pa, const int* pb, int n,
                     int2* binned, int* vals, int* off, int* bc, int* bsum,
                     hipStream_t stream) {
  constexpr int NBIN = nbin_of<MODE>();
  int nblk = (n + CHUNK - 1) / CHUNK;
  int len = NBIN * nblk;
  p1_hist<MODE><<<nblk, 256, 0, stream>>>(keys, n, bc, nblk);
  int nbs = (len + 255) / 256;
  scan_block<<<nbs, 256, 0, stream>>>(bc, bc, bsum, len);
  scan_top<<<1, 1024, 0, stream>>>(bsum, nbs);
  scan_addv<<<nbs, 256, 0, stream>>>(bc, bsum, len);
  p1_scatter<MODE><<<nblk, 256, 0, stream>>>(keys, pa, pb, n, bc, nblk, binned);
  p2_sort<MODE><<<NBIN, 256, 0, stream>>>(binned, bc, nblk, n, vals, off);
}

// ============================ launch ========================================
extern "C" void kernel_launch(void* const* d_in, const int* in_sizes, int n_in,
                              void* d_out, int out_size, void* d_ws, size_t ws_size,
                              hipStream_t stream) {
  const float* user_emb = (const float*)d_in[0];
  const float* ent_emb  = (const float*)d_in[1];
  const float* relw     = (const float*)d_in[2];
  const float* g1       = (const float*)d_in[3];
  const float* g2       = (const float*)d_in[4];
  const int*   head     = (const int*)d_in[5];
  const int*   tail     = (const int*)d_in[6];
  const int*   etype    = (const int*)d_in[7];
  const int*   mrow     = (const int*)d_in[8];
  const int*   mcol     = (const int*)d_in[9];

  const int n_edges = in_sizes[5];
  const int n_inter = in_sizes[8];
  const int n_hops  = in_sizes[3] / (D * D);

  // ---- workspace carve ----
  u16* entA_bf = (u16*)d_ws;
  u16* entB_bf = entA_bf + (size_t)N_ENT * D;
  u16* usr_bf  = entB_bf + (size_t)N_ENT * D;
  u16* fus_bf  = usr_bf + (size_t)N_USERS * D;
  float* ea_items = (float*)(fus_bf + (size_t)N_ITEMS * D);
  float* iu       = ea_items + (size_t)N_ITEMS * D;
  int* ip = (int*)(iu + (size_t)N_ITEMS * D);
  int* o_head = ip;   ip += N_ENT + 1;
  int* o_col  = ip;   ip += N_ITEMS + 1;
  int* o_row  = ip;   ip += N_USERS + 1;
  int* pk_head = ip;  ip += n_edges;   // packed tail|etype<<24, grouped by head
  int* vr_col  = ip;  ip += n_inter;   // mrow grouped by col
  int* vc_row  = ip;  ip += n_inter;   // mcol grouped by row
  int* bc      = ip;  ip += 391 * ((n_edges + CHUNK - 1) / CHUNK) + 1;  // blockcnt (max)
  int* bsum    = ip;  ip += 1024;

  float* out_ent = (float*)d_out;
  float* out_usr = out_ent + (size_t)N_ENT * D;

  // ---- sort temps live in d_out (overwritten by init_embed afterwards) ----
  int2* bin_head = (int2*)d_out;
  int2* bin_col  = bin_head + n_edges;
  int2* bin_row  = bin_col + n_inter;

  run_sort<0>(head, tail, etype, n_edges, bin_head, pk_head, o_head, bc, bsum, stream);
  run_sort<1>(mcol, mrow, nullptr, n_inter, bin_col, vr_col, o_col, bc, bsum, stream);
  run_sort<2>(mrow, mcol, nullptr, n_inter, bin_row, vc_row, o_row, bc, bsum, stream);

  // residual init AFTER sorting (d_out was scratch until here)
  init_embed<<<(N_ENT * D + 255) / 256, 256, 0, stream>>>(
      ent_emb, user_emb, out_ent, out_usr, entA_bf, usr_bf);

  for (int i = 0; i < n_hops; ++i) {
    const u16* ecur = (i & 1) ? entB_bf : entA_bf;
    u16* enxt       = (i & 1) ? entA_bf : entB_bf;

    kg_gather<<<(N_ENT + 3) / 4, 256, 0, stream>>>(
        ecur, relw, o_head, pk_head, ea_items, enxt, out_ent);

    inter_gather<<<(N_ITEMS + 3) / 4, 256, 0, stream>>>(
        usr_bf, relw, o_col, vr_col, iu);

    fuse_items<<<(N_ITEMS + 3) / 4, 256, 0, stream>>>(
        ea_items, iu, g1 + (size_t)i * D * D, g2 + (size_t)i * D * D,
        fus_bf, enxt, out_ent);

    user_gather<<<(N_USERS + 3) / 4, 256, 0, stream>>>(
        fus_bf, o_row, vc_row, usr_bf, out_usr);
  }
}